// Round 1
// baseline (3397.480 us; speedup 1.0000x reference)
//
#include <hip/hip_runtime.h>

#define LN_EPS 1e-5f

// ---------------------------------------------------------------------------
// Fused dense layer: Y = relu(LN(X @ W^T + b) * g + be)
// Block = 256 threads = 4 waves. Each block computes BM=32 rows x DOUT cols.
// Wave w owns rows {w, w+4, ..., w+28}; lane l owns cols {l, l+64, ...}.
// LN reduction is a pure wave-level shfl reduction (row lives in one wave).
// LDS staging stride SW=20 floats: float4-aligned (20%4==0) and lane stride
// 20 floats -> base banks cycle all multiples of 4 -> conflict-free b128.
// ---------------------------------------------------------------------------
template<int DOUT>
__global__ __launch_bounds__(256)
void layer_ln_relu(const float* __restrict__ X, const float* __restrict__ W,
                   const float* __restrict__ b, const float* __restrict__ g,
                   const float* __restrict__ be, float* __restrict__ Y, int DIN)
{
    constexpr int BM = 32, SW = 20, NJ = DOUT / 64;
    __shared__ float Ws[DOUT * SW];
    __shared__ float Xs[BM * SW];

    const int tid  = threadIdx.x;
    const int lane = tid & 63;
    const int wv   = tid >> 6;
    const long row0 = (long)blockIdx.x * BM;

    float acc[8][NJ];
#pragma unroll
    for (int i = 0; i < 8; ++i)
#pragma unroll
        for (int j = 0; j < NJ; ++j) acc[i][j] = 0.f;

    for (int k0 = 0; k0 < DIN; k0 += 16) {
        __syncthreads();
        // stage W tile: DOUT rows x 16 k, as float4s
        for (int idx = tid; idx < DOUT * 4; idx += 256) {
            int col = idx >> 2, q = idx & 3;
            float4 v = *(const float4*)(W + (long)col * DIN + k0 + q * 4);
            *(float4*)(&Ws[col * SW + q * 4]) = v;
        }
        // stage X tile: BM rows x 16 k
        for (int idx = tid; idx < BM * 4; idx += 256) {
            int r = idx >> 2, q = idx & 3;
            float4 v = *(const float4*)(X + (row0 + r) * DIN + k0 + q * 4);
            *(float4*)(&Xs[r * SW + q * 4]) = v;
        }
        __syncthreads();
#pragma unroll
        for (int q = 0; q < 4; ++q) {
            float4 xv[8], wf[NJ];
#pragma unroll
            for (int i = 0; i < 8; ++i)
                xv[i] = *(const float4*)(&Xs[(wv + 4 * i) * SW + q * 4]);  // broadcast
#pragma unroll
            for (int j = 0; j < NJ; ++j)
                wf[j] = *(const float4*)(&Ws[(lane + 64 * j) * SW + q * 4]);
#pragma unroll
            for (int i = 0; i < 8; ++i)
#pragma unroll
                for (int j = 0; j < NJ; ++j) {
                    acc[i][j] = fmaf(xv[i].x, wf[j].x, acc[i][j]);
                    acc[i][j] = fmaf(xv[i].y, wf[j].y, acc[i][j]);
                    acc[i][j] = fmaf(xv[i].z, wf[j].z, acc[i][j]);
                    acc[i][j] = fmaf(xv[i].w, wf[j].w, acc[i][j]);
                }
        }
    }

    // epilogue: bias + LayerNorm + affine + ReLU
    float bb[NJ], gg[NJ], bee[NJ];
#pragma unroll
    for (int j = 0; j < NJ; ++j) {
        int c = lane + 64 * j;
        bb[j] = b[c]; gg[j] = g[c]; bee[j] = be[c];
    }
#pragma unroll
    for (int i = 0; i < 8; ++i) {
        float s1 = 0.f, s2 = 0.f;
#pragma unroll
        for (int j = 0; j < NJ; ++j) {
            float a = acc[i][j] + bb[j];
            acc[i][j] = a;
            s1 += a; s2 += a * a;
        }
#pragma unroll
        for (int off = 32; off > 0; off >>= 1) {
            s1 += __shfl_xor(s1, off, 64);
            s2 += __shfl_xor(s2, off, 64);
        }
        float mean = s1 * (1.f / DOUT);
        float var  = s2 * (1.f / DOUT) - mean * mean;
        float inv  = rsqrtf(var + LN_EPS);
        long r = row0 + wv + 4 * i;
#pragma unroll
        for (int j = 0; j < NJ; ++j) {
            float v = (acc[i][j] - mean) * inv * gg[j] + bee[j];
            Y[r * DOUT + lane + 64 * j] = fmaxf(v, 0.f);
        }
    }
}

// ---------------------------------------------------------------------------
// Layer 4: Z = H @ W4^T + b4   (128 -> 32, no LN/ReLU). One thread per row.
// ---------------------------------------------------------------------------
__global__ __launch_bounds__(256)
void layer4_k(const float* __restrict__ H, const float* __restrict__ W4,
              const float* __restrict__ b4, float* __restrict__ Z)
{
    __shared__ float Ws[32 * 128];
    __shared__ float bs[32];
    const int tid = threadIdx.x;
    for (int idx = tid; idx < 4096; idx += 256) Ws[idx] = W4[idx];
    if (tid < 32) bs[tid] = b4[tid];
    __syncthreads();

    long r = (long)blockIdx.x * 256 + tid;
    float acc[32];
#pragma unroll
    for (int c = 0; c < 32; ++c) acc[c] = 0.f;
    for (int k = 0; k < 128; k += 4) {
        float4 x = *(const float4*)(H + r * 128 + k);
#pragma unroll
        for (int c = 0; c < 32; ++c) {
            acc[c] = fmaf(x.x, Ws[c * 128 + k + 0], acc[c]);
            acc[c] = fmaf(x.y, Ws[c * 128 + k + 1], acc[c]);
            acc[c] = fmaf(x.z, Ws[c * 128 + k + 2], acc[c]);
            acc[c] = fmaf(x.w, Ws[c * 128 + k + 3], acc[c]);
        }
    }
#pragma unroll
    for (int c = 0; c < 32; ++c) Z[r * 32 + c] = acc[c] + bs[c];
}

// ---------------------------------------------------------------------------
// Prototypes: one block per class, scan all 32768 support rows, no atomics.
// ---------------------------------------------------------------------------
__global__ __launch_bounds__(256)
void proto_k(const float* __restrict__ Zs, const int* __restrict__ lab,
             float* __restrict__ P)
{
    const int c = blockIdx.x;
    const int tid = threadIdx.x, lane = tid & 63, wv = tid >> 6;
    float acc[32];
#pragma unroll
    for (int d = 0; d < 32; ++d) acc[d] = 0.f;
    float cnt = 0.f;
    for (int i = tid; i < 32768; i += 256) {
        if (lab[i] == c) {
            cnt += 1.f;
#pragma unroll
            for (int d = 0; d < 32; ++d) acc[d] += Zs[(long)i * 32 + d];
        }
    }
    __shared__ float wsum[4][32];
    __shared__ float wcnt[4];
#pragma unroll
    for (int d = 0; d < 32; ++d) {
        float v = acc[d];
        for (int off = 32; off > 0; off >>= 1) v += __shfl_xor(v, off, 64);
        if (lane == 0) wsum[wv][d] = v;
    }
    {
        float v = cnt;
        for (int off = 32; off > 0; off >>= 1) v += __shfl_xor(v, off, 64);
        if (lane == 0) wcnt[wv] = v;
    }
    __syncthreads();
    if (tid < 32) {
        float s  = wsum[0][tid] + wsum[1][tid] + wsum[2][tid] + wsum[3][tid];
        float cn = wcnt[0] + wcnt[1] + wcnt[2] + wcnt[3];
        P[c * 32 + tid] = s / fmaxf(cn, 1.f);
    }
}

// ---------------------------------------------------------------------------
// -cdist: one thread per query row, protos in LDS.
// ---------------------------------------------------------------------------
__global__ __launch_bounds__(256)
void dist_k(const float* __restrict__ Zq, const float* __restrict__ P,
            float* __restrict__ O)
{
    __shared__ float ps[64 * 32];
    __shared__ float pn[64];
    const int tid = threadIdx.x;
    for (int idx = tid; idx < 2048; idx += 256) ps[idx] = P[idx];
    __syncthreads();
    if (tid < 64) {
        float s = 0.f;
        for (int d = 0; d < 32; ++d) { float v = ps[tid * 32 + d]; s += v * v; }
        pn[tid] = s;
    }
    __syncthreads();

    long q = (long)blockIdx.x * 256 + tid;
    float zr[32];
#pragma unroll
    for (int d = 0; d < 32; d += 4) {
        float4 v = *(const float4*)(Zq + q * 32 + d);
        zr[d] = v.x; zr[d + 1] = v.y; zr[d + 2] = v.z; zr[d + 3] = v.w;
    }
    float zz = 0.f;
#pragma unroll
    for (int d = 0; d < 32; ++d) zz += zr[d] * zr[d];
    for (int p = 0; p < 64; ++p) {
        float dot = 0.f;
#pragma unroll
        for (int d = 0; d < 32; ++d) dot = fmaf(zr[d], ps[p * 32 + d], dot);
        float sq = zz + pn[p] - 2.f * dot;
        O[q * 64 + p] = -sqrtf(fmaxf(sq, 0.f));
    }
}

// ---------------------------------------------------------------------------
// Host side
// ---------------------------------------------------------------------------
extern "C" void kernel_launch(void* const* d_in, const int* in_sizes, int n_in,
                              void* d_out, int out_size, void* d_ws, size_t ws_size,
                              hipStream_t stream)
{
    const float* supp = (const float*)d_in[0];   // [32768,768]
    const int*   lab  = (const int*)  d_in[1];   // [32768]
    const float* qry  = (const float*)d_in[2];   // [65536,768]
    const float* W1 = (const float*)d_in[3];  const float* b1 = (const float*)d_in[4];
    const float* g1 = (const float*)d_in[5];  const float* be1= (const float*)d_in[6];
    const float* W2 = (const float*)d_in[7];  const float* b2 = (const float*)d_in[8];
    const float* g2 = (const float*)d_in[9];  const float* be2= (const float*)d_in[10];
    const float* W3 = (const float*)d_in[11]; const float* b3 = (const float*)d_in[12];
    const float* g3 = (const float*)d_in[13]; const float* be3= (const float*)d_in[14];
    const float* W4 = (const float*)d_in[15]; const float* b4 = (const float*)d_in[16];
    float* out = (float*)d_out;                  // [65536,64]

    const long NTOT = 98304;   // 32768 support + 65536 query
    const long NS   = 32768;

    // workspace layout (floats): zAll [98304*32] | proto [2048] | bufA | bufB
    float* zAll  = (float*)d_ws;
    float* proto = zAll + NTOT * 32;
    float* bufA  = proto + 2048;
    size_t fixed_bytes = (size_t)(NTOT * 32 + 2048) * 4;

    // pick largest chunk (divisor of 32768) whose two 512-wide buffers fit ws
    long chunk = 32768;
    while (chunk > 2048 &&
           fixed_bytes + (size_t)chunk * 512 * 2 * 4 > ws_size)
        chunk >>= 1;
    float* bufB = bufA + chunk * 512;

    for (long r0 = 0; r0 < NTOT; r0 += chunk) {
        const float* X = (r0 < NS) ? (supp + r0 * 768)
                                   : (qry + (r0 - NS) * 768);
        layer_ln_relu<512><<<dim3(chunk / 32), dim3(256), 0, stream>>>(
            X, W1, b1, g1, be1, bufA, 768);
        layer_ln_relu<512><<<dim3(chunk / 32), dim3(256), 0, stream>>>(
            bufA, W2, b2, g2, be2, bufB, 512);
        layer_ln_relu<128><<<dim3(chunk / 32), dim3(256), 0, stream>>>(
            bufB, W3, b3, g3, be3, bufA, 512);
        layer4_k<<<dim3(chunk / 256), dim3(256), 0, stream>>>(
            bufA, W4, b4, zAll + r0 * 32);
    }

    proto_k<<<dim3(64), dim3(256), 0, stream>>>(zAll, lab, proto);
    dist_k<<<dim3(256), dim3(256), 0, stream>>>(zAll + NS * 32, proto, out);
}

// Round 2
// 2201.332 us; speedup vs baseline: 1.5434x; 1.5434x over previous
//
#include <hip/hip_runtime.h>

typedef unsigned short u16;
typedef short bf16x8 __attribute__((ext_vector_type(8)));
typedef float f32x16 __attribute__((ext_vector_type(16)));
typedef unsigned short u16x4 __attribute__((ext_vector_type(4)));

#define LN_EPS 1e-5f

__device__ __forceinline__ u16 f2bf(float v) {
    unsigned x = __float_as_uint(v);
    x += 0x7fffu + ((x >> 16) & 1u);        // RNE to bf16
    return (u16)(x >> 16);
}
__device__ __forceinline__ float bf2f(u16 u) {
    return __uint_as_float(((unsigned)u) << 16);
}

#define GLD16(gp, lp) __builtin_amdgcn_global_load_lds( \
    (const __attribute__((address_space(1))) void*)(gp), \
    (__attribute__((address_space(3))) void*)(lp), 16, 0, 0)

// ---------------------------------------------------------------------------
// fp32 -> (hi, lo) bf16 planes.  x = hi + lo to ~2^-17 relative.
// ---------------------------------------------------------------------------
__global__ __launch_bounds__(256)
void split_k(const float* __restrict__ src, u16* __restrict__ hi,
             u16* __restrict__ lo, long n4)
{
    long i = (long)blockIdx.x * 256 + threadIdx.x;
    long stride = (long)gridDim.x * 256;
    for (; i < n4; i += stride) {
        float4 v = ((const float4*)src)[i];
        u16x4 h, l;
        h.x = f2bf(v.x); l.x = f2bf(v.x - bf2f(h.x));
        h.y = f2bf(v.y); l.y = f2bf(v.y - bf2f(h.y));
        h.z = f2bf(v.z); l.z = f2bf(v.z - bf2f(h.z));
        h.w = f2bf(v.w); l.w = f2bf(v.w - bf2f(h.w));
        ((u16x4*)hi)[i] = h;
        ((u16x4*)lo)[i] = l;
    }
}

// ---------------------------------------------------------------------------
// Fused split-bf16 MFMA layer: Y = relu(LN(X @ W^T + b) * g + be)
// 3-pass split: acc += xh*wh + xh*wl + xl*wh  (~fp32 accuracy).
// Block = 256 thr = 4 waves, tile = 64 rows x DOUT cols (LN fully in-block).
// Wave w covers cols [w*DOUT/4, (w+1)*DOUT/4); 2 m-tiles x NT n-tiles of
// 32x32x16 MFMA. LDS is chunked 16B/(half,row) so global_load_lds's
// uniform-base+lane*16 order IS the layout, and every frag read is 32
// consecutive chunks per half-wave (conflict-free).
// C/D layout: col=lane&31, row=(reg&3)+8*(reg>>2)+4*(lane>>5)  [m74/m101].
// ---------------------------------------------------------------------------
template<int DOUT, bool OUT_SPLIT>
__global__ __launch_bounds__(256)
void mfma_layer(const u16* __restrict__ Ah, const u16* __restrict__ Al,
                const u16* __restrict__ Wh, const u16* __restrict__ Wl,
                const float* __restrict__ bias, const float* __restrict__ gam,
                const float* __restrict__ bet,
                u16* __restrict__ Yh, u16* __restrict__ Yl,
                float* __restrict__ Yf, int DIN)
{
    constexpr int NT  = DOUT / 128;   // n-tiles per wave (4 or 1)
    constexpr int WIN = DOUT / 64;    // W row-blocks per k-half window

    __shared__ __align__(16) u16 AhL[2 * 64 * 8];
    __shared__ __align__(16) u16 AlL[2 * 64 * 8];
    __shared__ __align__(16) u16 WhL[2 * DOUT * 8];
    __shared__ __align__(16) u16 WlL[2 * DOUT * 8];
    __shared__ float lnp[4][64][2];

    const int tid  = threadIdx.x;
    const int lane = tid & 63, wv = tid >> 6;
    const int l31  = lane & 31, hh = lane >> 5;
    const long row0 = (long)blockIdx.x * 64;

    f32x16 acc[2][NT];
#pragma unroll
    for (int t = 0; t < 2; ++t)
#pragma unroll
        for (int u = 0; u < NT; ++u)
#pragma unroll
            for (int e = 0; e < 16; ++e) acc[t][u][e] = 0.f;

    for (int k0 = 0; k0 < DIN; k0 += 16) {
        __syncthreads();
        // stage A hi/lo: 4 insts total, one per wave. window h2 = k-half.
        {
            const u16* gp = ((wv & 2) ? Al : Ah) + (row0 + lane) * DIN + k0 + (wv & 1) * 8;
            u16* lp = ((wv & 2) ? AlL : AhL) + ((wv & 1) * 64) * 8;
            GLD16(gp, lp);
        }
        // stage W hi/lo: 4*WIN insts split across waves
        for (int i = wv; i < 4 * WIN; i += 4) {
            int pl  = i / (2 * WIN);
            int rem = i % (2 * WIN);
            int h2  = rem / WIN;
            int j   = rem % WIN;
            const u16* gp = (pl ? Wl : Wh) + (long)(j * 64 + lane) * DIN + k0 + h2 * 8;
            u16* lp = (pl ? WlL : WhL) + (h2 * DOUT + j * 64) * 8;
            GLD16(gp, lp);
        }
        __syncthreads();

        bf16x8 af[2][2], wf[NT][2];
#pragma unroll
        for (int t = 0; t < 2; ++t) {
            af[t][0] = *(const bf16x8*)(AhL + (hh * 64 + t * 32 + l31) * 8);
            af[t][1] = *(const bf16x8*)(AlL + (hh * 64 + t * 32 + l31) * 8);
        }
#pragma unroll
        for (int u = 0; u < NT; ++u) {
            int nc = hh * DOUT + wv * (DOUT / 4) + u * 32 + l31;
            wf[u][0] = *(const bf16x8*)(WhL + nc * 8);
            wf[u][1] = *(const bf16x8*)(WlL + nc * 8);
        }
#pragma unroll
        for (int t = 0; t < 2; ++t)
#pragma unroll
            for (int u = 0; u < NT; ++u) {
                acc[t][u] = __builtin_amdgcn_mfma_f32_32x32x16_bf16(af[t][0], wf[u][0], acc[t][u], 0, 0, 0);
                acc[t][u] = __builtin_amdgcn_mfma_f32_32x32x16_bf16(af[t][0], wf[u][1], acc[t][u], 0, 0, 0);
                acc[t][u] = __builtin_amdgcn_mfma_f32_32x32x16_bf16(af[t][1], wf[u][0], acc[t][u], 0, 0, 0);
            }
    }

    // ---------------- epilogue: bias + LayerNorm + affine + relu ----------
    float gg[NT], bb[NT], bev[NT];
#pragma unroll
    for (int u = 0; u < NT; ++u) {
        int c = wv * (DOUT / 4) + u * 32 + l31;
        bb[u] = bias[c]; gg[u] = gam[c]; bev[u] = bet[c];
    }
#pragma unroll
    for (int t = 0; t < 2; ++t)
#pragma unroll
        for (int r = 0; r < 16; ++r) {
            float s1 = 0.f, s2 = 0.f;
#pragma unroll
            for (int u = 0; u < NT; ++u) {
                float v = acc[t][u][r] + bb[u];
                acc[t][u][r] = v;
                s1 += v; s2 += v * v;
            }
#pragma unroll
            for (int off = 1; off < 32; off <<= 1) {
                s1 += __shfl_xor(s1, off, 64);
                s2 += __shfl_xor(s2, off, 64);
            }
            int row = t * 32 + (r & 3) + 8 * (r >> 2) + 4 * hh;
            if (l31 == r) { lnp[wv][row][0] = s1; lnp[wv][row][1] = s2; }
        }
    __syncthreads();
#pragma unroll
    for (int t = 0; t < 2; ++t)
#pragma unroll
        for (int r = 0; r < 16; ++r) {
            int row = t * 32 + (r & 3) + 8 * (r >> 2) + 4 * hh;
            float s1 = lnp[0][row][0] + lnp[1][row][0] + lnp[2][row][0] + lnp[3][row][0];
            float s2 = lnp[0][row][1] + lnp[1][row][1] + lnp[2][row][1] + lnp[3][row][1];
            float mean = s1 * (1.f / DOUT);
            float inv  = rsqrtf(s2 * (1.f / DOUT) - mean * mean + LN_EPS);
            long gr = row0 + row;
#pragma unroll
            for (int u = 0; u < NT; ++u) {
                int c = wv * (DOUT / 4) + u * 32 + l31;
                float v = (acc[t][u][r] - mean) * inv * gg[u] + bev[u];
                v = fmaxf(v, 0.f);
                if (OUT_SPLIT) {
                    u16 hv = f2bf(v);
                    Yh[gr * DOUT + c] = hv;
                    Yl[gr * DOUT + c] = f2bf(v - bf2f(hv));
                } else {
                    Yf[gr * DOUT + c] = v;
                }
            }
        }
}

// ---------------------------------------------------------------------------
// Layer 4: Z = H @ W4^T + b4   (128 -> 32, fp32). One thread per row.
// ---------------------------------------------------------------------------
__global__ __launch_bounds__(256)
void layer4_k(const float* __restrict__ H, const float* __restrict__ W4,
              const float* __restrict__ b4, float* __restrict__ Z)
{
    __shared__ float Ws[32 * 128];
    __shared__ float bs[32];
    const int tid = threadIdx.x;
    for (int idx = tid; idx < 4096; idx += 256) Ws[idx] = W4[idx];
    if (tid < 32) bs[tid] = b4[tid];
    __syncthreads();

    long r = (long)blockIdx.x * 256 + tid;
    float acc[32];
#pragma unroll
    for (int c = 0; c < 32; ++c) acc[c] = 0.f;
    for (int k = 0; k < 128; k += 4) {
        float4 x = *(const float4*)(H + r * 128 + k);
#pragma unroll
        for (int c = 0; c < 32; ++c) {
            acc[c] = fmaf(x.x, Ws[c * 128 + k + 0], acc[c]);
            acc[c] = fmaf(x.y, Ws[c * 128 + k + 1], acc[c]);
            acc[c] = fmaf(x.z, Ws[c * 128 + k + 2], acc[c]);
            acc[c] = fmaf(x.w, Ws[c * 128 + k + 3], acc[c]);
        }
    }
#pragma unroll
    for (int c = 0; c < 32; ++c) Z[r * 32 + c] = acc[c] + bs[c];
}

// ---------------------------------------------------------------------------
// Prototypes: one block per class, no atomics.
// ---------------------------------------------------------------------------
__global__ __launch_bounds__(256)
void proto_k(const float* __restrict__ Zs, const int* __restrict__ lab,
             float* __restrict__ P)
{
    const int c = blockIdx.x;
    const int tid = threadIdx.x, lane = tid & 63, wv = tid >> 6;
    float acc[32];
#pragma unroll
    for (int d = 0; d < 32; ++d) acc[d] = 0.f;
    float cnt = 0.f;
    for (int i = tid; i < 32768; i += 256) {
        if (lab[i] == c) {
            cnt += 1.f;
#pragma unroll
            for (int d = 0; d < 32; ++d) acc[d] += Zs[(long)i * 32 + d];
        }
    }
    __shared__ float wsum[4][32];
    __shared__ float wcnt[4];
#pragma unroll
    for (int d = 0; d < 32; ++d) {
        float v = acc[d];
        for (int off = 32; off > 0; off >>= 1) v += __shfl_xor(v, off, 64);
        if (lane == 0) wsum[wv][d] = v;
    }
    {
        float v = cnt;
        for (int off = 32; off > 0; off >>= 1) v += __shfl_xor(v, off, 64);
        if (lane == 0) wcnt[wv] = v;
    }
    __syncthreads();
    if (tid < 32) {
        float s  = wsum[0][tid] + wsum[1][tid] + wsum[2][tid] + wsum[3][tid];
        float cn = wcnt[0] + wcnt[1] + wcnt[2] + wcnt[3];
        P[c * 32 + tid] = s / fmaxf(cn, 1.f);
    }
}

// ---------------------------------------------------------------------------
// -cdist: one thread per query row, protos in LDS.
// ---------------------------------------------------------------------------
__global__ __launch_bounds__(256)
void dist_k(const float* __restrict__ Zq, const float* __restrict__ P,
            float* __restrict__ O)
{
    __shared__ float ps[64 * 32];
    __shared__ float pn[64];
    const int tid = threadIdx.x;
    for (int idx = tid; idx < 2048; idx += 256) ps[idx] = P[idx];
    __syncthreads();
    if (tid < 64) {
        float s = 0.f;
        for (int d = 0; d < 32; ++d) { float v = ps[tid * 32 + d]; s += v * v; }
        pn[tid] = s;
    }
    __syncthreads();

    long q = (long)blockIdx.x * 256 + tid;
    float zr[32];
#pragma unroll
    for (int d = 0; d < 32; d += 4) {
        float4 v = *(const float4*)(Zq + q * 32 + d);
        zr[d] = v.x; zr[d + 1] = v.y; zr[d + 2] = v.z; zr[d + 3] = v.w;
    }
    float zz = 0.f;
#pragma unroll
    for (int d = 0; d < 32; ++d) zz += zr[d] * zr[d];
    for (int p = 0; p < 64; ++p) {
        float dot = 0.f;
#pragma unroll
        for (int d = 0; d < 32; ++d) dot = fmaf(zr[d], ps[p * 32 + d], dot);
        float sq = zz + pn[p] - 2.f * dot;
        O[q * 64 + p] = -sqrtf(fmaxf(sq, 0.f));
    }
}

// ---------------------------------------------------------------------------
// Host side
// ---------------------------------------------------------------------------
extern "C" void kernel_launch(void* const* d_in, const int* in_sizes, int n_in,
                              void* d_out, int out_size, void* d_ws, size_t ws_size,
                              hipStream_t stream)
{
    const float* supp = (const float*)d_in[0];   // [32768,768]
    const int*   lab  = (const int*)  d_in[1];   // [32768]
    const float* qry  = (const float*)d_in[2];   // [65536,768]
    const float* W1 = (const float*)d_in[3];  const float* b1 = (const float*)d_in[4];
    const float* g1 = (const float*)d_in[5];  const float* be1= (const float*)d_in[6];
    const float* W2 = (const float*)d_in[7];  const float* b2 = (const float*)d_in[8];
    const float* g2 = (const float*)d_in[9];  const float* be2= (const float*)d_in[10];
    const float* W3 = (const float*)d_in[11]; const float* b3 = (const float*)d_in[12];
    const float* g3 = (const float*)d_in[13]; const float* be3= (const float*)d_in[14];
    const float* W4 = (const float*)d_in[15]; const float* b4 = (const float*)d_in[16];
    float* out = (float*)d_out;                  // [65536,64]

    const long NTOT = 98304, NS = 32768;

    char* wsp = (char*)d_ws;
    size_t off = 0;
    auto take = [&](size_t bytes) {
        char* p = wsp + off;
        off += (bytes + 255) & ~(size_t)255;
        return (void*)p;
    };

    float* zAll  = (float*)take((size_t)NTOT * 32 * 4);
    float* proto = (float*)take(2048 * 4);
    u16* W1h = (u16*)take((size_t)512 * 768 * 2);
    u16* W1l = (u16*)take((size_t)512 * 768 * 2);
    u16* W2h = (u16*)take((size_t)512 * 512 * 2);
    u16* W2l = (u16*)take((size_t)512 * 512 * 2);
    u16* W3h = (u16*)take((size_t)128 * 512 * 2);
    u16* W3l = (u16*)take((size_t)128 * 512 * 2);
    size_t fixed = off;

    long C = 32768;
    while (C > 2048 && fixed + (size_t)7680 * C + 16 * 256 > ws_size) C >>= 1;

    u16*   Xh  = (u16*)take((size_t)C * 768 * 2);
    u16*   Xl  = (u16*)take((size_t)C * 768 * 2);
    u16*   h1h = (u16*)take((size_t)C * 512 * 2);
    u16*   h1l = (u16*)take((size_t)C * 512 * 2);
    u16*   h2h = (u16*)take((size_t)C * 512 * 2);
    u16*   h2l = (u16*)take((size_t)C * 512 * 2);
    float* h3  = (float*)take((size_t)C * 128 * 4);

    // split weights (tiny)
    split_k<<<dim3(384), dim3(256), 0, stream>>>(W1, W1h, W1l, 512 * 768 / 4);
    split_k<<<dim3(256), dim3(256), 0, stream>>>(W2, W2h, W2l, 512 * 512 / 4);
    split_k<<<dim3(64),  dim3(256), 0, stream>>>(W3, W3h, W3l, 128 * 512 / 4);

    for (long r0 = 0; r0 < NTOT; r0 += C) {
        const float* X = (r0 < NS) ? (supp + r0 * 768) : (qry + (r0 - NS) * 768);
        split_k<<<dim3(2048), dim3(256), 0, stream>>>(X, Xh, Xl, C * 768 / 4);
        mfma_layer<512, true><<<dim3(C / 64), dim3(256), 0, stream>>>(
            Xh, Xl, W1h, W1l, b1, g1, be1, h1h, h1l, nullptr, 768);
        mfma_layer<512, true><<<dim3(C / 64), dim3(256), 0, stream>>>(
            h1h, h1l, W2h, W2l, b2, g2, be2, h2h, h2l, nullptr, 512);
        mfma_layer<128, false><<<dim3(C / 64), dim3(256), 0, stream>>>(
            h2h, h2l, W3h, W3l, b3, g3, be3, nullptr, nullptr, h3, 512);
        layer4_k<<<dim3(C / 256), dim3(256), 0, stream>>>(h3, W4, b4, zAll + r0 * 32);
    }

    proto_k<<<dim3(64),  dim3(256), 0, stream>>>(zAll, lab, proto);
    dist_k<<<dim3(256), dim3(256), 0, stream>>>(zAll + NS * 32, proto, out);
}

// Round 3
// 1425.836 us; speedup vs baseline: 2.3828x; 1.5439x over previous
//
#include <hip/hip_runtime.h>

typedef unsigned short u16;
typedef short bf16x8 __attribute__((ext_vector_type(8)));
typedef float f32x16 __attribute__((ext_vector_type(16)));
typedef unsigned short u16x8v __attribute__((ext_vector_type(8)));

#define LN_EPS 1e-5f

__device__ __forceinline__ u16 f2bf(float v) {
    unsigned x = __float_as_uint(v);
    x += 0x7fffu + ((x >> 16) & 1u);        // RNE to bf16
    return (u16)(x >> 16);
}
__device__ __forceinline__ float bf2f(u16 u) {
    return __uint_as_float(((unsigned)u) << 16);
}

#define GLD16(gp, lp) __builtin_amdgcn_global_load_lds( \
    (const __attribute__((address_space(1))) void*)(gp), \
    (__attribute__((address_space(3))) void*)(lp), 16, 0, 0)

// ---------------------------------------------------------------------------
// fp32 [R][DIN] row-major  ->  hi/lo bf16 planes in MFMA-staging layout
// [DIN/8][R][8]  (16B chunk of 8 k per row, grouped by k-chunk).
// Reads: per-lane row-gather (L1 line reuse across adjacent chunks).
// Writes: lane-consecutive 16B -> fully coalesced.
// ---------------------------------------------------------------------------
__global__ __launch_bounds__(64)
void swizzle_split(const float* __restrict__ src, u16* __restrict__ hi,
                   u16* __restrict__ lo, int R, int DIN)
{
    const int lane = threadIdx.x;
    const long r = (long)blockIdx.x * 64 + lane;
    const int NC = DIN >> 3;
    const int kc0 = (NC >> 2) * blockIdx.y;
    const int kc1 = kc0 + (NC >> 2);
    const float* sp = src + r * DIN;
    for (int kc = kc0; kc < kc1; ++kc) {
        float4 a = *(const float4*)(sp + kc * 8);
        float4 b = *(const float4*)(sp + kc * 8 + 4);
        float v[8] = {a.x, a.y, a.z, a.w, b.x, b.y, b.z, b.w};
        u16x8v h, l;
#pragma unroll
        for (int j = 0; j < 8; ++j) {
            u16 hb = f2bf(v[j]);
            h[j] = hb;
            l[j] = f2bf(v[j] - bf2f(hb));
        }
        long o = ((long)kc * R + r) * 8;
        *(u16x8v*)(hi + o) = h;
        *(u16x8v*)(lo + o) = l;
    }
}

// ---------------------------------------------------------------------------
// Fused split-bf16 MFMA layer: Y = relu(LN(X @ W^T + b) * g + be)
// 3-pass split: acc += xh*wh + xh*wl + xl*wh (~fp32 accuracy).
// Operands pre-swizzled [k/8][row][8]; global_load_lds is lane-consecutive
// 16B (coalesced) and lands in LDS in exactly frag-read order.
// Block = 4 waves, 64 rows x DOUT. __launch_bounds__(256,2) caps VGPR<=256
// so 2 blocks/CU co-reside (barrier overlap across blocks).
// ---------------------------------------------------------------------------
template<int DOUT, bool OUT_SPLIT>
__global__ __launch_bounds__(256, 2)
void mfma_layer(const u16* __restrict__ Ah, const u16* __restrict__ Al,
                const u16* __restrict__ Wh, const u16* __restrict__ Wl,
                const float* __restrict__ bias, const float* __restrict__ gam,
                const float* __restrict__ bet,
                u16* __restrict__ Yh, u16* __restrict__ Yl,
                float* __restrict__ Yf, int DIN, int NR)
{
    constexpr int NT  = DOUT / 128;   // n-tiles per wave
    constexpr int NWI = DOUT / 64;    // W 64-row groups per chunk
    constexpr int NI  = (4 + 4 * NWI) / 4;  // GLD16 insts per wave

    __shared__ __align__(16) u16 AL[2][2 * 64 * 8];     // [plane][chunk][64row][8]
    __shared__ __align__(16) u16 WL[2][2 * DOUT * 8];   // [plane][chunk][DOUT][8]
    __shared__ float lnp[4][64][2];

    const int tid  = threadIdx.x;
    const int lane = tid & 63, wv = tid >> 6;
    const int l31  = lane & 31, hh = lane >> 5;
    const long row0 = (long)blockIdx.x * 64;

    // precompute per-wave staging descriptors (ptrs advance, LDS dst fixed)
    const u16* gpp[NI];
    u16* lpp[NI];
    long stp[NI];
#pragma unroll
    for (int t = 0; t < NI; ++t) {
        int i = wv + 4 * t;
        if (i < 4) {                       // A: plane p, chunk c
            int p = i >> 1, c = i & 1;
            const u16* base = p ? Al : Ah;
            gpp[t] = base + ((long)c * NR + row0 + lane) * 8;
            lpp[t] = AL[p] + (size_t)(c * 64) * 8;
            stp[t] = (long)2 * NR * 8;
        } else {                           // W: plane p, chunk c, row-group j
            int idx = i - 4;
            int p   = idx / (2 * NWI);
            int rem = idx % (2 * NWI);
            int c = rem / NWI, j = rem % NWI;
            const u16* base = p ? Wl : Wh;
            gpp[t] = base + ((long)c * DOUT + j * 64 + lane) * 8;
            lpp[t] = WL[p] + (size_t)(c * DOUT + j * 64) * 8;
            stp[t] = (long)2 * DOUT * 8;
        }
    }

    f32x16 acc[2][NT];
#pragma unroll
    for (int t = 0; t < 2; ++t)
#pragma unroll
        for (int u = 0; u < NT; ++u)
#pragma unroll
            for (int e = 0; e < 16; ++e) acc[t][u][e] = 0.f;

    for (int ks = 0; ks < DIN / 16; ++ks) {
        __syncthreads();
#pragma unroll
        for (int t = 0; t < NI; ++t) {
            GLD16(gpp[t], lpp[t]);
            gpp[t] += stp[t];
        }
        __syncthreads();

        bf16x8 af[2][2], wf[NT][2];
#pragma unroll
        for (int t = 0; t < 2; ++t)
#pragma unroll
            for (int p = 0; p < 2; ++p)
                af[t][p] = *(const bf16x8*)(AL[p] + (size_t)(hh * 64 + t * 32 + l31) * 8);
#pragma unroll
        for (int u = 0; u < NT; ++u)
#pragma unroll
            for (int p = 0; p < 2; ++p)
                wf[u][p] = *(const bf16x8*)(WL[p] + (size_t)(hh * DOUT + wv * (DOUT / 4) + u * 32 + l31) * 8);

#pragma unroll
        for (int t = 0; t < 2; ++t)
#pragma unroll
            for (int u = 0; u < NT; ++u) {
                acc[t][u] = __builtin_amdgcn_mfma_f32_32x32x16_bf16(af[t][0], wf[u][0], acc[t][u], 0, 0, 0);
                acc[t][u] = __builtin_amdgcn_mfma_f32_32x32x16_bf16(af[t][0], wf[u][1], acc[t][u], 0, 0, 0);
                acc[t][u] = __builtin_amdgcn_mfma_f32_32x32x16_bf16(af[t][1], wf[u][0], acc[t][u], 0, 0, 0);
            }
    }

    // ---------------- epilogue: bias + LayerNorm + affine + relu ----------
    float gg[NT], bb[NT], bev[NT];
#pragma unroll
    for (int u = 0; u < NT; ++u) {
        int c = wv * (DOUT / 4) + u * 32 + l31;
        bb[u] = bias[c]; gg[u] = gam[c]; bev[u] = bet[c];
    }
#pragma unroll
    for (int t = 0; t < 2; ++t)
#pragma unroll
        for (int r = 0; r < 16; ++r) {
            float s1 = 0.f, s2 = 0.f;
#pragma unroll
            for (int u = 0; u < NT; ++u) {
                float v = acc[t][u][r] + bb[u];
                acc[t][u][r] = v;
                s1 += v; s2 += v * v;
            }
#pragma unroll
            for (int off = 1; off < 32; off <<= 1) {
                s1 += __shfl_xor(s1, off, 64);
                s2 += __shfl_xor(s2, off, 64);
            }
            int row = t * 32 + (r & 3) + 8 * (r >> 2) + 4 * hh;
            if (l31 == r) { lnp[wv][row][0] = s1; lnp[wv][row][1] = s2; }
        }
    __syncthreads();
#pragma unroll
    for (int t = 0; t < 2; ++t)
#pragma unroll
        for (int r = 0; r < 16; ++r) {
            int row = t * 32 + (r & 3) + 8 * (r >> 2) + 4 * hh;
            float s1 = lnp[0][row][0] + lnp[1][row][0] + lnp[2][row][0] + lnp[3][row][0];
            float s2 = lnp[0][row][1] + lnp[1][row][1] + lnp[2][row][1] + lnp[3][row][1];
            float mean = s1 * (1.f / DOUT);
            float inv  = rsqrtf(s2 * (1.f / DOUT) - mean * mean + LN_EPS);
            long gr = row0 + row;
#pragma unroll
            for (int u = 0; u < NT; ++u) {
                int c = wv * (DOUT / 4) + u * 32 + l31;
                float v = (acc[t][u][r] - mean) * inv * gg[u] + bev[u];
                v = fmaxf(v, 0.f);
                if (OUT_SPLIT) {
                    u16 hv = f2bf(v);
                    long o = ((long)(c >> 3) * NR + gr) * 8 + (c & 7);
                    Yh[o] = hv;
                    Yl[o] = f2bf(v - bf2f(hv));
                } else {
                    Yf[gr * DOUT + c] = v;
                }
            }
        }
}

// ---------------------------------------------------------------------------
// Layer 4: Z = H @ W4^T + b4   (128 -> 32, fp32). One thread per row.
// ---------------------------------------------------------------------------
__global__ __launch_bounds__(256)
void layer4_k(const float* __restrict__ H, const float* __restrict__ W4,
              const float* __restrict__ b4, float* __restrict__ Z)
{
    __shared__ float Ws[32 * 128];
    __shared__ float bs[32];
    const int tid = threadIdx.x;
    for (int idx = tid; idx < 4096; idx += 256) Ws[idx] = W4[idx];
    if (tid < 32) bs[tid] = b4[tid];
    __syncthreads();

    long r = (long)blockIdx.x * 256 + tid;
    float acc[32];
#pragma unroll
    for (int c = 0; c < 32; ++c) acc[c] = 0.f;
    for (int k = 0; k < 128; k += 4) {
        float4 x = *(const float4*)(H + r * 128 + k);
#pragma unroll
        for (int c = 0; c < 32; ++c) {
            acc[c] = fmaf(x.x, Ws[c * 128 + k + 0], acc[c]);
            acc[c] = fmaf(x.y, Ws[c * 128 + k + 1], acc[c]);
            acc[c] = fmaf(x.z, Ws[c * 128 + k + 2], acc[c]);
            acc[c] = fmaf(x.w, Ws[c * 128 + k + 3], acc[c]);
        }
    }
#pragma unroll
    for (int c = 0; c < 32; ++c) Z[r * 32 + c] = acc[c] + bs[c];
}

// ---------------------------------------------------------------------------
// Prototypes: one block per class, no atomics.
// ---------------------------------------------------------------------------
__global__ __launch_bounds__(256)
void proto_k(const float* __restrict__ Zs, const int* __restrict__ lab,
             float* __restrict__ P)
{
    const int c = blockIdx.x;
    const int tid = threadIdx.x, lane = tid & 63, wv = tid >> 6;
    float acc[32];
#pragma unroll
    for (int d = 0; d < 32; ++d) acc[d] = 0.f;
    float cnt = 0.f;
    for (int i = tid; i < 32768; i += 256) {
        if (lab[i] == c) {
            cnt += 1.f;
#pragma unroll
            for (int d = 0; d < 32; ++d) acc[d] += Zs[(long)i * 32 + d];
        }
    }
    __shared__ float wsum[4][32];
    __shared__ float wcnt[4];
#pragma unroll
    for (int d = 0; d < 32; ++d) {
        float v = acc[d];
        for (int off = 32; off > 0; off >>= 1) v += __shfl_xor(v, off, 64);
        if (lane == 0) wsum[wv][d] = v;
    }
    {
        float v = cnt;
        for (int off = 32; off > 0; off >>= 1) v += __shfl_xor(v, off, 64);
        if (lane == 0) wcnt[wv] = v;
    }
    __syncthreads();
    if (tid < 32) {
        float s  = wsum[0][tid] + wsum[1][tid] + wsum[2][tid] + wsum[3][tid];
        float cn = wcnt[0] + wcnt[1] + wcnt[2] + wcnt[3];
        P[c * 32 + tid] = s / fmaxf(cn, 1.f);
    }
}

// ---------------------------------------------------------------------------
// -cdist: one thread per query row, protos in LDS.
// ---------------------------------------------------------------------------
__global__ __launch_bounds__(256)
void dist_k(const float* __restrict__ Zq, const float* __restrict__ P,
            float* __restrict__ O)
{
    __shared__ float ps[64 * 32];
    __shared__ float pn[64];
    const int tid = threadIdx.x;
    for (int idx = tid; idx < 2048; idx += 256) ps[idx] = P[idx];
    __syncthreads();
    if (tid < 64) {
        float s = 0.f;
        for (int d = 0; d < 32; ++d) { float v = ps[tid * 32 + d]; s += v * v; }
        pn[tid] = s;
    }
    __syncthreads();

    long q = (long)blockIdx.x * 256 + tid;
    float zr[32];
#pragma unroll
    for (int d = 0; d < 32; d += 4) {
        float4 v = *(const float4*)(Zq + q * 32 + d);
        zr[d] = v.x; zr[d + 1] = v.y; zr[d + 2] = v.z; zr[d + 3] = v.w;
    }
    float zz = 0.f;
#pragma unroll
    for (int d = 0; d < 32; ++d) zz += zr[d] * zr[d];
    for (int p = 0; p < 64; ++p) {
        float dot = 0.f;
#pragma unroll
        for (int d = 0; d < 32; ++d) dot = fmaf(zr[d], ps[p * 32 + d], dot);
        float sq = zz + pn[p] - 2.f * dot;
        O[q * 64 + p] = -sqrtf(fmaxf(sq, 0.f));
    }
}

// ---------------------------------------------------------------------------
// Host side
// ---------------------------------------------------------------------------
extern "C" void kernel_launch(void* const* d_in, const int* in_sizes, int n_in,
                              void* d_out, int out_size, void* d_ws, size_t ws_size,
                              hipStream_t stream)
{
    const float* supp = (const float*)d_in[0];   // [32768,768]
    const int*   lab  = (const int*)  d_in[1];   // [32768]
    const float* qry  = (const float*)d_in[2];   // [65536,768]
    const float* W1 = (const float*)d_in[3];  const float* b1 = (const float*)d_in[4];
    const float* g1 = (const float*)d_in[5];  const float* be1= (const float*)d_in[6];
    const float* W2 = (const float*)d_in[7];  const float* b2 = (const float*)d_in[8];
    const float* g2 = (const float*)d_in[9];  const float* be2= (const float*)d_in[10];
    const float* W3 = (const float*)d_in[11]; const float* b3 = (const float*)d_in[12];
    const float* g3 = (const float*)d_in[13]; const float* be3= (const float*)d_in[14];
    const float* W4 = (const float*)d_in[15]; const float* b4 = (const float*)d_in[16];
    float* out = (float*)d_out;                  // [65536,64]

    const long NTOT = 98304, NS = 32768;

    char* wsp = (char*)d_ws;
    size_t off = 0;
    auto take = [&](size_t bytes) {
        char* p = wsp + off;
        off += (bytes + 255) & ~(size_t)255;
        return (void*)p;
    };

    float* zAll  = (float*)take((size_t)NTOT * 32 * 4);
    float* proto = (float*)take(2048 * 4);
    u16* W1h = (u16*)take((size_t)512 * 768 * 2);
    u16* W1l = (u16*)take((size_t)512 * 768 * 2);
    u16* W2h = (u16*)take((size_t)512 * 512 * 2);
    u16* W2l = (u16*)take((size_t)512 * 512 * 2);
    u16* W3h = (u16*)take((size_t)128 * 512 * 2);
    u16* W3l = (u16*)take((size_t)128 * 512 * 2);
    size_t fixed = off;

    long C = 32768;
    while (C > 2048 && fixed + (size_t)7680 * C + 16 * 256 > ws_size) C >>= 1;

    u16*   Xh  = (u16*)take((size_t)C * 768 * 2);
    u16*   Xl  = (u16*)take((size_t)C * 768 * 2);
    u16*   h1h = (u16*)take((size_t)C * 512 * 2);
    u16*   h1l = (u16*)take((size_t)C * 512 * 2);
    u16*   h2h = (u16*)take((size_t)C * 512 * 2);
    u16*   h2l = (u16*)take((size_t)C * 512 * 2);
    float* h3  = (float*)take((size_t)C * 128 * 4);

    // split+swizzle weights (tiny)
    swizzle_split<<<dim3(8, 4), dim3(64), 0, stream>>>(W1, W1h, W1l, 512, 768);
    swizzle_split<<<dim3(8, 4), dim3(64), 0, stream>>>(W2, W2h, W2l, 512, 512);
    swizzle_split<<<dim3(2, 4), dim3(64), 0, stream>>>(W3, W3h, W3l, 128, 512);

    for (long r0 = 0; r0 < NTOT; r0 += C) {
        const float* X = (r0 < NS) ? (supp + r0 * 768) : (qry + (r0 - NS) * 768);
        swizzle_split<<<dim3(C / 64, 4), dim3(64), 0, stream>>>(X, Xh, Xl, (int)C, 768);
        mfma_layer<512, true><<<dim3(C / 64), dim3(256), 0, stream>>>(
            Xh, Xl, W1h, W1l, b1, g1, be1, h1h, h1l, nullptr, 768, (int)C);
        mfma_layer<512, true><<<dim3(C / 64), dim3(256), 0, stream>>>(
            h1h, h1l, W2h, W2l, b2, g2, be2, h2h, h2l, nullptr, 512, (int)C);
        mfma_layer<128, false><<<dim3(C / 64), dim3(256), 0, stream>>>(
            h2h, h2l, W3h, W3l, b3, g3, be3, nullptr, nullptr, h3, 512, (int)C);
        layer4_k<<<dim3(C / 256), dim3(256), 0, stream>>>(h3, W4, b4, zAll + r0 * 32);
    }

    proto_k<<<dim3(64),  dim3(256), 0, stream>>>(zAll, lab, proto);
    dist_k<<<dim3(256), dim3(256), 0, stream>>>(zAll + NS * 32, proto, out);
}

// Round 4
// 1276.502 us; speedup vs baseline: 2.6616x; 1.1170x over previous
//
#include <hip/hip_runtime.h>

typedef unsigned short u16;
typedef short bf16x8 __attribute__((ext_vector_type(8)));
typedef float f32x16 __attribute__((ext_vector_type(16)));
typedef unsigned short u16x4v __attribute__((ext_vector_type(4)));
typedef unsigned short u16x8v __attribute__((ext_vector_type(8)));

#define LN_EPS 1e-5f

__device__ __forceinline__ u16 f2bf(float v) {
    unsigned x = __float_as_uint(v);
    x += 0x7fffu + ((x >> 16) & 1u);        // RNE to bf16
    return (u16)(x >> 16);
}
__device__ __forceinline__ float bf2f(u16 u) {
    return __uint_as_float(((unsigned)u) << 16);
}

#define GLD16(gp, lp) __builtin_amdgcn_global_load_lds( \
    (const __attribute__((address_space(1))) void*)(gp), \
    (__attribute__((address_space(3))) void*)(lp), 16, 0, 0)

// ---------------------------------------------------------------------------
// fp32 [R][DIN] row-major -> hi/lo bf16 planes, MFMA-staging layout
// [DIN/8][R][8]. v2: coalesced float4 reads (lane order follows k within a
// row), LDS transpose (row dim padded to 17 to break bank alignment),
// coalesced 16B chunk writes (16 consecutive rows = 256B segments).
// grid = (R/16, 4), block = 256.
// ---------------------------------------------------------------------------
__global__ __launch_bounds__(256)
void swizzle_split(const float* __restrict__ src, u16* __restrict__ hi,
                   u16* __restrict__ lo, int R, int DIN)
{
    __shared__ __align__(16) u16 SH[2][24][17][8];   // [plane][kc][row(pad)][8]
    const int tid  = threadIdx.x;
    const int row0 = blockIdx.x * 16;
    const int QK   = DIN / 16;          // float4 slots per row per quarter
    const int kq0  = QK * blockIdx.y;   // float4 offset of this quarter
    const int NKC  = DIN / 32;          // 16B k-chunks per quarter (<=24)

    // phase 1: read + split + LDS-transpose
    const int slots = 16 * QK;
    for (int s = tid; s < slots; s += 256) {
        int row = s / QK, kq = s % QK;
        float4 v = *(const float4*)(src + (long)(row0 + row) * DIN + (long)(kq0 + kq) * 4);
        int kc = kq >> 1, jh = (kq & 1) * 4;
        float vv[4] = {v.x, v.y, v.z, v.w};
        u16x4v h, l;
#pragma unroll
        for (int j = 0; j < 4; ++j) {
            u16 hb = f2bf(vv[j]);
            h[j] = hb;
            l[j] = f2bf(vv[j] - bf2f(hb));
        }
        *(u16x4v*)(&SH[0][kc][row][jh]) = h;
        *(u16x4v*)(&SH[1][kc][row][jh]) = l;
    }
    __syncthreads();
    // phase 2: coalesced chunk writes
    const int chunks = NKC * 16;
    for (int s = tid; s < chunks; s += 256) {
        int row = s & 15, kc = s >> 4;
        long o = ((long)(kq0 / 2 + kc) * R + row0 + row) * 8;
        *(u16x8v*)(hi + o) = *(const u16x8v*)(&SH[0][kc][row][0]);
        *(u16x8v*)(lo + o) = *(const u16x8v*)(&SH[1][kc][row][0]);
    }
}

// ---------------------------------------------------------------------------
// Fused split-bf16 MFMA layer: Y = relu(LN(X @ W^T + b) * g + be)
// 3-pass split: acc += xh*wh + xh*wl + xl*wh (~fp32 accuracy).
//
// v4 structure:
//  - W frags: DIRECT global->VGPR loads from the swizzled [kc][col][8]
//    layout (per-wave cols are disjoint -> same L2 traffic as LDS staging,
//    zero LDS cost, no barrier dependency; compiler pipelines via vmcnt).
//  - A: staged via global_load_lds in slabs of 4 k-steps, double-buffered
//    (32KB LDS) -> ONE barrier per 4 k-steps, prefetch issued right after
//    each barrier with a full slab of compute to cover it.
// Block = 4 waves, 64 rows x DOUT; wave wv owns cols [wv*DOUT/4, ...).
// C/D layout: col=lane&31, row=(reg&3)+8*(reg>>2)+4*(lane>>5)  [m74/m101].
// ---------------------------------------------------------------------------
template<int DOUT, bool OUT_SPLIT>
__global__ __launch_bounds__(256, 2)
void mfma_layer(const u16* __restrict__ Ah, const u16* __restrict__ Al,
                const u16* __restrict__ Wh, const u16* __restrict__ Wl,
                const float* __restrict__ bias, const float* __restrict__ gam,
                const float* __restrict__ bet,
                u16* __restrict__ Yh, u16* __restrict__ Yl,
                float* __restrict__ Yf, int DIN, int NR)
{
    constexpr int NT = DOUT / 128;            // n-tiles per wave (4 or 1)

    // A slab: [buf][step(4)][plane(2)][chunk(2)][64 rows][8]  = 2 x 16KB
    __shared__ __align__(16) u16 AL[2][4][2][2][64 * 8];
    __shared__ float lnp[4][64][2];

    const int tid  = threadIdx.x;
    const int lane = tid & 63, wv = tid >> 6;
    const int l31  = lane & 31, hh = lane >> 5;
    const long row0 = (long)blockIdx.x * 64;

    // A staging: wave wv stages step s=wv of each slab (4 GLD16: plane x chunk)
    const u16* gpA[4];
    const long stA = (long)8 * NR * 8;        // advance 8 k-chunks per slab
#pragma unroll
    for (int t = 0; t < 4; ++t) {
        int p = t & 1, c = t >> 1;
        const u16* base = p ? Al : Ah;
        gpA[t] = base + ((long)(2 * wv + c) * NR + row0 + lane) * 8;
    }

    f32x16 acc[2][NT];
#pragma unroll
    for (int t = 0; t < 2; ++t)
#pragma unroll
        for (int u = 0; u < NT; ++u)
#pragma unroll
            for (int e = 0; e < 16; ++e) acc[t][u][e] = 0.f;

    const int nslab = DIN / 64;
    // prologue: slab 0 -> buf 0
#pragma unroll
    for (int t = 0; t < 4; ++t) {
        GLD16(gpA[t], &AL[0][wv][t & 1][t >> 1][0]);
        gpA[t] += stA;
    }

    for (int sl = 0; sl < nslab; ++sl) {
        __syncthreads();                       // slab sl ready (drains vmcnt)
        const int cb = sl & 1;
        if (sl + 1 < nslab) {                  // prefetch next slab
#pragma unroll
            for (int t = 0; t < 4; ++t) {
                GLD16(gpA[t], &AL[cb ^ 1][wv][t & 1][t >> 1][0]);
                gpA[t] += stA;
            }
        }
#pragma unroll
        for (int s = 0; s < 4; ++s) {
            const int ks = sl * 4 + s;
            bf16x8 wf[NT][2], af[2][2];
#pragma unroll
            for (int u = 0; u < NT; ++u) {
                long wo = ((long)(2 * ks + hh) * DOUT + wv * (DOUT / 4) + u * 32 + l31) * 8;
                wf[u][0] = *(const bf16x8*)(Wh + wo);
                wf[u][1] = *(const bf16x8*)(Wl + wo);
            }
#pragma unroll
            for (int t = 0; t < 2; ++t) {
                af[t][0] = *(const bf16x8*)(&AL[cb][s][0][hh][(t * 32 + l31) * 8]);
                af[t][1] = *(const bf16x8*)(&AL[cb][s][1][hh][(t * 32 + l31) * 8]);
            }
#pragma unroll
            for (int t = 0; t < 2; ++t)
#pragma unroll
                for (int u = 0; u < NT; ++u) {
                    acc[t][u] = __builtin_amdgcn_mfma_f32_32x32x16_bf16(af[t][0], wf[u][0], acc[t][u], 0, 0, 0);
                    acc[t][u] = __builtin_amdgcn_mfma_f32_32x32x16_bf16(af[t][0], wf[u][1], acc[t][u], 0, 0, 0);
                    acc[t][u] = __builtin_amdgcn_mfma_f32_32x32x16_bf16(af[t][1], wf[u][0], acc[t][u], 0, 0, 0);
                }
        }
    }

    // ---------------- epilogue: bias + LayerNorm + affine + relu ----------
    float gg[NT], bb[NT], bev[NT];
#pragma unroll
    for (int u = 0; u < NT; ++u) {
        int c = wv * (DOUT / 4) + u * 32 + l31;
        bb[u] = bias[c]; gg[u] = gam[c]; bev[u] = bet[c];
    }
#pragma unroll
    for (int t = 0; t < 2; ++t)
#pragma unroll
        for (int r = 0; r < 16; ++r) {
            float s1 = 0.f, s2 = 0.f;
#pragma unroll
            for (int u = 0; u < NT; ++u) {
                float v = acc[t][u][r] + bb[u];
                acc[t][u][r] = v;
                s1 += v; s2 += v * v;
            }
#pragma unroll
            for (int off = 1; off < 32; off <<= 1) {
                s1 += __shfl_xor(s1, off, 64);
                s2 += __shfl_xor(s2, off, 64);
            }
            int row = t * 32 + (r & 3) + 8 * (r >> 2) + 4 * hh;
            if (l31 == r) { lnp[wv][row][0] = s1; lnp[wv][row][1] = s2; }
        }
    __syncthreads();
#pragma unroll
    for (int t = 0; t < 2; ++t)
#pragma unroll
        for (int r = 0; r < 16; ++r) {
            int row = t * 32 + (r & 3) + 8 * (r >> 2) + 4 * hh;
            float s1 = lnp[0][row][0] + lnp[1][row][0] + lnp[2][row][0] + lnp[3][row][0];
            float s2 = lnp[0][row][1] + lnp[1][row][1] + lnp[2][row][1] + lnp[3][row][1];
            float mean = s1 * (1.f / DOUT);
            float inv  = rsqrtf(s2 * (1.f / DOUT) - mean * mean + LN_EPS);
            long gr = row0 + row;
#pragma unroll
            for (int u = 0; u < NT; ++u) {
                int c = wv * (DOUT / 4) + u * 32 + l31;
                float v = (acc[t][u][r] - mean) * inv * gg[u] + bev[u];
                v = fmaxf(v, 0.f);
                if (OUT_SPLIT) {
                    u16 hv = f2bf(v);
                    long o = ((long)(c >> 3) * NR + gr) * 8 + (c & 7);
                    Yh[o] = hv;
                    Yl[o] = f2bf(v - bf2f(hv));
                } else {
                    Yf[gr * DOUT + c] = v;
                }
            }
        }
}

// ---------------------------------------------------------------------------
// Layer 4: Z = H @ W4^T + b4   (128 -> 32, fp32). One thread per row.
// ---------------------------------------------------------------------------
__global__ __launch_bounds__(256)
void layer4_k(const float* __restrict__ H, const float* __restrict__ W4,
              const float* __restrict__ b4, float* __restrict__ Z)
{
    __shared__ float Ws[32 * 128];
    __shared__ float bs[32];
    const int tid = threadIdx.x;
    for (int idx = tid; idx < 4096; idx += 256) Ws[idx] = W4[idx];
    if (tid < 32) bs[tid] = b4[tid];
    __syncthreads();

    long r = (long)blockIdx.x * 256 + tid;
    float acc[32];
#pragma unroll
    for (int c = 0; c < 32; ++c) acc[c] = 0.f;
    for (int k = 0; k < 128; k += 4) {
        float4 x = *(const float4*)(H + r * 128 + k);
#pragma unroll
        for (int c = 0; c < 32; ++c) {
            acc[c] = fmaf(x.x, Ws[c * 128 + k + 0], acc[c]);
            acc[c] = fmaf(x.y, Ws[c * 128 + k + 1], acc[c]);
            acc[c] = fmaf(x.z, Ws[c * 128 + k + 2], acc[c]);
            acc[c] = fmaf(x.w, Ws[c * 128 + k + 3], acc[c]);
        }
    }
#pragma unroll
    for (int c = 0; c < 32; ++c) Z[r * 32 + c] = acc[c] + bs[c];
}

// ---------------------------------------------------------------------------
// Prototypes: one block per class, no atomics.
// ---------------------------------------------------------------------------
__global__ __launch_bounds__(256)
void proto_k(const float* __restrict__ Zs, const int* __restrict__ lab,
             float* __restrict__ P)
{
    const int c = blockIdx.x;
    const int tid = threadIdx.x, lane = tid & 63, wv = tid >> 6;
    float acc[32];
#pragma unroll
    for (int d = 0; d < 32; ++d) acc[d] = 0.f;
    float cnt = 0.f;
    for (int i = tid; i < 32768; i += 256) {
        if (lab[i] == c) {
            cnt += 1.f;
#pragma unroll
            for (int d = 0; d < 32; ++d) acc[d] += Zs[(long)i * 32 + d];
        }
    }
    __shared__ float wsum[4][32];
    __shared__ float wcnt[4];
#pragma unroll
    for (int d = 0; d < 32; ++d) {
        float v = acc[d];
        for (int off = 32; off > 0; off >>= 1) v += __shfl_xor(v, off, 64);
        if (lane == 0) wsum[wv][d] = v;
    }
    {
        float v = cnt;
        for (int off = 32; off > 0; off >>= 1) v += __shfl_xor(v, off, 64);
        if (lane == 0) wcnt[wv] = v;
    }
    __syncthreads();
    if (tid < 32) {
        float s  = wsum[0][tid] + wsum[1][tid] + wsum[2][tid] + wsum[3][tid];
        float cn = wcnt[0] + wcnt[1] + wcnt[2] + wcnt[3];
        P[c * 32 + tid] = s / fmaxf(cn, 1.f);
    }
}

// ---------------------------------------------------------------------------
// -cdist: one thread per query row, protos in LDS.
// ---------------------------------------------------------------------------
__global__ __launch_bounds__(256)
void dist_k(const float* __restrict__ Zq, const float* __restrict__ P,
            float* __restrict__ O)
{
    __shared__ float ps[64 * 32];
    __shared__ float pn[64];
    const int tid = threadIdx.x;
    for (int idx = tid; idx < 2048; idx += 256) ps[idx] = P[idx];
    __syncthreads();
    if (tid < 64) {
        float s = 0.f;
        for (int d = 0; d < 32; ++d) { float v = ps[tid * 32 + d]; s += v * v; }
        pn[tid] = s;
    }
    __syncthreads();

    long q = (long)blockIdx.x * 256 + tid;
    float zr[32];
#pragma unroll
    for (int d = 0; d < 32; d += 4) {
        float4 v = *(const float4*)(Zq + q * 32 + d);
        zr[d] = v.x; zr[d + 1] = v.y; zr[d + 2] = v.z; zr[d + 3] = v.w;
    }
    float zz = 0.f;
#pragma unroll
    for (int d = 0; d < 32; ++d) zz += zr[d] * zr[d];
    for (int p = 0; p < 64; ++p) {
        float dot = 0.f;
#pragma unroll
        for (int d = 0; d < 32; ++d) dot = fmaf(zr[d], ps[p * 32 + d], dot);
        float sq = zz + pn[p] - 2.f * dot;
        O[q * 64 + p] = -sqrtf(fmaxf(sq, 0.f));
    }
}

// ---------------------------------------------------------------------------
// Host side
// ---------------------------------------------------------------------------
extern "C" void kernel_launch(void* const* d_in, const int* in_sizes, int n_in,
                              void* d_out, int out_size, void* d_ws, size_t ws_size,
                              hipStream_t stream)
{
    const float* supp = (const float*)d_in[0];   // [32768,768]
    const int*   lab  = (const int*)  d_in[1];   // [32768]
    const float* qry  = (const float*)d_in[2];   // [65536,768]
    const float* W1 = (const float*)d_in[3];  const float* b1 = (const float*)d_in[4];
    const float* g1 = (const float*)d_in[5];  const float* be1= (const float*)d_in[6];
    const float* W2 = (const float*)d_in[7];  const float* b2 = (const float*)d_in[8];
    const float* g2 = (const float*)d_in[9];  const float* be2= (const float*)d_in[10];
    const float* W3 = (const float*)d_in[11]; const float* b3 = (const float*)d_in[12];
    const float* g3 = (const float*)d_in[13]; const float* be3= (const float*)d_in[14];
    const float* W4 = (const float*)d_in[15]; const float* b4 = (const float*)d_in[16];
    float* out = (float*)d_out;                  // [65536,64]

    const long NTOT = 98304, NS = 32768;

    char* wsp = (char*)d_ws;
    size_t off = 0;
    auto take = [&](size_t bytes) {
        char* p = wsp + off;
        off += (bytes + 255) & ~(size_t)255;
        return (void*)p;
    };

    float* zAll  = (float*)take((size_t)NTOT * 32 * 4);
    float* proto = (float*)take(2048 * 4);
    u16* W1h = (u16*)take((size_t)512 * 768 * 2);
    u16* W1l = (u16*)take((size_t)512 * 768 * 2);
    u16* W2h = (u16*)take((size_t)512 * 512 * 2);
    u16* W2l = (u16*)take((size_t)512 * 512 * 2);
    u16* W3h = (u16*)take((size_t)128 * 512 * 2);
    u16* W3l = (u16*)take((size_t)128 * 512 * 2);
    size_t fixed = off;

    long C = 32768;
    while (C > 2048 && fixed + (size_t)7680 * C + 16 * 256 > ws_size) C >>= 1;

    u16*   Xh  = (u16*)take((size_t)C * 768 * 2);
    u16*   Xl  = (u16*)take((size_t)C * 768 * 2);
    u16*   h1h = (u16*)take((size_t)C * 512 * 2);
    u16*   h1l = (u16*)take((size_t)C * 512 * 2);
    u16*   h2h = (u16*)take((size_t)C * 512 * 2);
    u16*   h2l = (u16*)take((size_t)C * 512 * 2);
    float* h3  = (float*)take((size_t)C * 128 * 4);

    // split+swizzle weights (tiny)
    swizzle_split<<<dim3(32, 4), dim3(256), 0, stream>>>(W1, W1h, W1l, 512, 768);
    swizzle_split<<<dim3(32, 4), dim3(256), 0, stream>>>(W2, W2h, W2l, 512, 512);
    swizzle_split<<<dim3(8, 4),  dim3(256), 0, stream>>>(W3, W3h, W3l, 128, 512);

    for (long r0 = 0; r0 < NTOT; r0 += C) {
        const float* X = (r0 < NS) ? (supp + r0 * 768) : (qry + (r0 - NS) * 768);
        swizzle_split<<<dim3(C / 16, 4), dim3(256), 0, stream>>>(X, Xh, Xl, (int)C, 768);
        mfma_layer<512, true><<<dim3(C / 64), dim3(256), 0, stream>>>(
            Xh, Xl, W1h, W1l, b1, g1, be1, h1h, h1l, nullptr, 768, (int)C);
        mfma_layer<512, true><<<dim3(C / 64), dim3(256), 0, stream>>>(
            h1h, h1l, W2h, W2l, b2, g2, be2, h2h, h2l, nullptr, 512, (int)C);
        mfma_layer<128, false><<<dim3(C / 64), dim3(256), 0, stream>>>(
            h2h, h2l, W3h, W3l, b3, g3, be3, nullptr, nullptr, h3, 512, (int)C);
        layer4_k<<<dim3(C / 256), dim3(256), 0, stream>>>(h3, W4, b4, zAll + r0 * 32);
    }

    proto_k<<<dim3(64),  dim3(256), 0, stream>>>(zAll, lab, proto);
    dist_k<<<dim3(256), dim3(256), 0, stream>>>(zAll + NS * 32, proto, out);
}

// Round 5
// 1011.162 us; speedup vs baseline: 3.3600x; 1.2624x over previous
//
#include <hip/hip_runtime.h>

typedef unsigned short u16;
typedef short bf16x8 __attribute__((ext_vector_type(8)));
typedef float f32x16 __attribute__((ext_vector_type(16)));
typedef unsigned short u16x4v __attribute__((ext_vector_type(4)));
typedef unsigned short u16x8v __attribute__((ext_vector_type(8)));

#define LN_EPS 1e-5f

__device__ __forceinline__ u16 f2bf(float v) {
    unsigned x = __float_as_uint(v);
    x += 0x7fffu + ((x >> 16) & 1u);        // RNE to bf16
    return (u16)(x >> 16);
}
__device__ __forceinline__ float bf2f(u16 u) {
    return __uint_as_float(((unsigned)u) << 16);
}

#define GLD16(gp, lp) __builtin_amdgcn_global_load_lds( \
    (const __attribute__((address_space(1))) void*)(gp), \
    (__attribute__((address_space(3))) void*)(lp), 16, 0, 0)

// ---------------------------------------------------------------------------
// fp32 [R][DIN] row-major -> hi/lo bf16 planes, MFMA-staging layout
// [DIN/8][R][8]. Used for WEIGHTS only (tiny). Coalesced reads, LDS
// transpose, coalesced 16B chunk writes. grid = (R/16, 4), block = 256.
// ---------------------------------------------------------------------------
__global__ __launch_bounds__(256)
void swizzle_split(const float* __restrict__ src, u16* __restrict__ hi,
                   u16* __restrict__ lo, int R, int DIN)
{
    __shared__ __align__(16) u16 SH[2][24][17][8];   // [plane][kc][row(pad)][8]
    const int tid  = threadIdx.x;
    const int row0 = blockIdx.x * 16;
    const int QK   = DIN / 16;          // float4 slots per row per quarter
    const int kq0  = QK * blockIdx.y;   // float4 offset of this quarter
    const int NKC  = DIN / 32;          // 16B k-chunks per quarter (<=24)

    const int slots = 16 * QK;
    for (int s = tid; s < slots; s += 256) {
        int row = s / QK, kq = s % QK;
        float4 v = *(const float4*)(src + (long)(row0 + row) * DIN + (long)(kq0 + kq) * 4);
        int kc = kq >> 1, jh = (kq & 1) * 4;
        float vv[4] = {v.x, v.y, v.z, v.w};
        u16x4v h, l;
#pragma unroll
        for (int j = 0; j < 4; ++j) {
            u16 hb = f2bf(vv[j]);
            h[j] = hb;
            l[j] = f2bf(vv[j] - bf2f(hb));
        }
        *(u16x4v*)(&SH[0][kc][row][jh]) = h;
        *(u16x4v*)(&SH[1][kc][row][jh]) = l;
    }
    __syncthreads();
    const int chunks = NKC * 16;
    for (int s = tid; s < chunks; s += 256) {
        int row = s & 15, kc = s >> 4;
        long o = ((long)(kq0 / 2 + kc) * R + row0 + row) * 8;
        *(u16x8v*)(hi + o) = *(const u16x8v*)(&SH[0][kc][row][0]);
        *(u16x8v*)(lo + o) = *(const u16x8v*)(&SH[1][kc][row][0]);
    }
}

// ---------------------------------------------------------------------------
// Shared epilogue: bias + LayerNorm + affine + relu, then store (optionally
// re-split to swizzled hi/lo bf16 for the next layer).
// C/D layout: col=lane&31, row=(reg&3)+8*(reg>>2)+4*(lane>>5)  [m74/m101].
// ---------------------------------------------------------------------------
template<int DOUT, bool OUT_SPLIT, int NT>
__device__ __forceinline__ void ln_epilogue(
    f32x16 (&acc)[2][NT], float (&lnp)[4][64][2],
    const float* __restrict__ bias, const float* __restrict__ gam,
    const float* __restrict__ bet,
    u16* __restrict__ Yh, u16* __restrict__ Yl, float* __restrict__ Yf,
    long row0, int NR, int wv, int l31, int hh)
{
    float gg[NT], bb[NT], bev[NT];
#pragma unroll
    for (int u = 0; u < NT; ++u) {
        int c = wv * (DOUT / 4) + u * 32 + l31;
        bb[u] = bias[c]; gg[u] = gam[c]; bev[u] = bet[c];
    }
#pragma unroll
    for (int t = 0; t < 2; ++t)
#pragma unroll
        for (int r = 0; r < 16; ++r) {
            float s1 = 0.f, s2 = 0.f;
#pragma unroll
            for (int u = 0; u < NT; ++u) {
                float v = acc[t][u][r] + bb[u];
                acc[t][u][r] = v;
                s1 += v; s2 += v * v;
            }
#pragma unroll
            for (int off = 1; off < 32; off <<= 1) {
                s1 += __shfl_xor(s1, off, 64);
                s2 += __shfl_xor(s2, off, 64);
            }
            int row = t * 32 + (r & 3) + 8 * (r >> 2) + 4 * hh;
            if (l31 == r) { lnp[wv][row][0] = s1; lnp[wv][row][1] = s2; }
        }
    __syncthreads();
#pragma unroll
    for (int t = 0; t < 2; ++t)
#pragma unroll
        for (int r = 0; r < 16; ++r) {
            int row = t * 32 + (r & 3) + 8 * (r >> 2) + 4 * hh;
            float s1 = lnp[0][row][0] + lnp[1][row][0] + lnp[2][row][0] + lnp[3][row][0];
            float s2 = lnp[0][row][1] + lnp[1][row][1] + lnp[2][row][1] + lnp[3][row][1];
            float mean = s1 * (1.f / DOUT);
            float inv  = rsqrtf(s2 * (1.f / DOUT) - mean * mean + LN_EPS);
            long gr = row0 + row;
#pragma unroll
            for (int u = 0; u < NT; ++u) {
                int c = wv * (DOUT / 4) + u * 32 + l31;
                float v = (acc[t][u][r] - mean) * inv * gg[u] + bev[u];
                v = fmaxf(v, 0.f);
                if (OUT_SPLIT) {
                    u16 hv = f2bf(v);
                    long o = ((long)(c >> 3) * NR + gr) * 8 + (c & 7);
                    Yh[o] = hv;
                    Yl[o] = f2bf(v - bf2f(hv));
                } else {
                    Yf[gr * DOUT + c] = v;
                }
            }
        }
}

// ---------------------------------------------------------------------------
// Layer 1: fp32 X input, FUSED split. Per slab (64 k), each thread loads 16
// consecutive fp32 of one row (coalesced 256B per 4 lanes), converts to
// hi/lo bf16 in-register, ds_writes into the double-buffered padded slab.
// W frags: direct global->VGPR from swizzled [kc][col][8] (L2-resident).
// Slab stride padded to 520 u16: frag reads conflict-free, writes <=4-way.
// ---------------------------------------------------------------------------
template<int DOUT>
__global__ __launch_bounds__(256, 2)
void mfma_layer1(const float* __restrict__ X,
                 const u16* __restrict__ Wh, const u16* __restrict__ Wl,
                 const float* __restrict__ bias, const float* __restrict__ gam,
                 const float* __restrict__ bet,
                 u16* __restrict__ Yh, u16* __restrict__ Yl,
                 int DIN, int NR, long rbase)
{
    constexpr int NT = DOUT / 128;
    __shared__ __align__(16) u16 AL[2][4][2][2][520]; // [buf][step][plane][chunk][pad]
    __shared__ float lnp[4][64][2];

    const int tid  = threadIdx.x;
    const int lane = tid & 63, wv = tid >> 6;
    const int l31  = lane & 31, hh = lane >> 5;
    const long lrow0 = (long)blockIdx.x * 64;      // row in this X source
    const long row0  = rbase + lrow0;              // global row for output

    const int srow  = wv * 16 + (lane >> 2);       // staging row this thread owns
    const int kpart = lane & 3;                    // which 16-k step it stages
    const float* xp = X + (lrow0 + srow) * DIN + kpart * 16;

    f32x16 acc[2][NT];
#pragma unroll
    for (int t = 0; t < 2; ++t)
#pragma unroll
        for (int u = 0; u < NT; ++u)
#pragma unroll
            for (int e = 0; e < 16; ++e) acc[t][u][e] = 0.f;

    const int nslab = DIN / 64;

    auto stage = [&](const float* p, int buf) {
#pragma unroll
        for (int c = 0; c < 2; ++c) {
            float4 v0 = *(const float4*)(p + c * 8);
            float4 v1 = *(const float4*)(p + c * 8 + 4);
            float f[8] = {v0.x, v0.y, v0.z, v0.w, v1.x, v1.y, v1.z, v1.w};
            u16x8v h, l;
#pragma unroll
            for (int j = 0; j < 8; ++j) {
                u16 hb = f2bf(f[j]);
                h[j] = hb;
                l[j] = f2bf(f[j] - bf2f(hb));
            }
            *(u16x8v*)(&AL[buf][kpart][0][c][srow * 8]) = h;
            *(u16x8v*)(&AL[buf][kpart][1][c][srow * 8]) = l;
        }
    };

    stage(xp, 0);                                   // prologue: slab 0
    for (int sl = 0; sl < nslab; ++sl) {
        __syncthreads();
        const int cb = sl & 1;
        if (sl + 1 < nslab) stage(xp + (sl + 1) * 64, cb ^ 1);
#pragma unroll
        for (int s = 0; s < 4; ++s) {
            const int ks = sl * 4 + s;
            bf16x8 wf[NT][2], af[2][2];
#pragma unroll
            for (int u = 0; u < NT; ++u) {
                long wo = ((long)(2 * ks + hh) * DOUT + wv * (DOUT / 4) + u * 32 + l31) * 8;
                wf[u][0] = *(const bf16x8*)(Wh + wo);
                wf[u][1] = *(const bf16x8*)(Wl + wo);
            }
#pragma unroll
            for (int t = 0; t < 2; ++t) {
                af[t][0] = *(const bf16x8*)(&AL[cb][s][0][hh][(t * 32 + l31) * 8]);
                af[t][1] = *(const bf16x8*)(&AL[cb][s][1][hh][(t * 32 + l31) * 8]);
            }
#pragma unroll
            for (int t = 0; t < 2; ++t)
#pragma unroll
                for (int u = 0; u < NT; ++u) {
                    acc[t][u] = __builtin_amdgcn_mfma_f32_32x32x16_bf16(af[t][0], wf[u][0], acc[t][u], 0, 0, 0);
                    acc[t][u] = __builtin_amdgcn_mfma_f32_32x32x16_bf16(af[t][0], wf[u][1], acc[t][u], 0, 0, 0);
                    acc[t][u] = __builtin_amdgcn_mfma_f32_32x32x16_bf16(af[t][1], wf[u][0], acc[t][u], 0, 0, 0);
                }
        }
    }

    ln_epilogue<DOUT, true, NT>(acc, lnp, bias, gam, bet, Yh, Yl, nullptr,
                                row0, NR, wv, l31, hh);
}

// ---------------------------------------------------------------------------
// Layers 2/3: pre-swizzled hi/lo bf16 A input via GLD16 slab double-buffer.
// W frags direct global->VGPR. One barrier per 4 k-steps.
// ---------------------------------------------------------------------------
template<int DOUT, bool OUT_SPLIT>
__global__ __launch_bounds__(256, 2)
void mfma_layer(const u16* __restrict__ Ah, const u16* __restrict__ Al,
                const u16* __restrict__ Wh, const u16* __restrict__ Wl,
                const float* __restrict__ bias, const float* __restrict__ gam,
                const float* __restrict__ bet,
                u16* __restrict__ Yh, u16* __restrict__ Yl,
                float* __restrict__ Yf, int DIN, int NR)
{
    constexpr int NT = DOUT / 128;
    __shared__ __align__(16) u16 AL[2][4][2][2][64 * 8];
    __shared__ float lnp[4][64][2];

    const int tid  = threadIdx.x;
    const int lane = tid & 63, wv = tid >> 6;
    const int l31  = lane & 31, hh = lane >> 5;
    const long row0 = (long)blockIdx.x * 64;

    const u16* gpA[4];
    const long stA = (long)8 * NR * 8;
#pragma unroll
    for (int t = 0; t < 4; ++t) {
        int p = t & 1, c = t >> 1;
        const u16* base = p ? Al : Ah;
        gpA[t] = base + ((long)(2 * wv + c) * NR + row0 + lane) * 8;
    }

    f32x16 acc[2][NT];
#pragma unroll
    for (int t = 0; t < 2; ++t)
#pragma unroll
        for (int u = 0; u < NT; ++u)
#pragma unroll
            for (int e = 0; e < 16; ++e) acc[t][u][e] = 0.f;

    const int nslab = DIN / 64;
#pragma unroll
    for (int t = 0; t < 4; ++t) {
        GLD16(gpA[t], &AL[0][wv][t & 1][t >> 1][0]);
        gpA[t] += stA;
    }

    for (int sl = 0; sl < nslab; ++sl) {
        __syncthreads();
        const int cb = sl & 1;
        if (sl + 1 < nslab) {
#pragma unroll
            for (int t = 0; t < 4; ++t) {
                GLD16(gpA[t], &AL[cb ^ 1][wv][t & 1][t >> 1][0]);
                gpA[t] += stA;
            }
        }
#pragma unroll
        for (int s = 0; s < 4; ++s) {
            const int ks = sl * 4 + s;
            bf16x8 wf[NT][2], af[2][2];
#pragma unroll
            for (int u = 0; u < NT; ++u) {
                long wo = ((long)(2 * ks + hh) * DOUT + wv * (DOUT / 4) + u * 32 + l31) * 8;
                wf[u][0] = *(const bf16x8*)(Wh + wo);
                wf[u][1] = *(const bf16x8*)(Wl + wo);
            }
#pragma unroll
            for (int t = 0; t < 2; ++t) {
                af[t][0] = *(const bf16x8*)(&AL[cb][s][0][hh][(t * 32 + l31) * 8]);
                af[t][1] = *(const bf16x8*)(&AL[cb][s][1][hh][(t * 32 + l31) * 8]);
            }
#pragma unroll
            for (int t = 0; t < 2; ++t)
#pragma unroll
                for (int u = 0; u < NT; ++u) {
                    acc[t][u] = __builtin_amdgcn_mfma_f32_32x32x16_bf16(af[t][0], wf[u][0], acc[t][u], 0, 0, 0);
                    acc[t][u] = __builtin_amdgcn_mfma_f32_32x32x16_bf16(af[t][0], wf[u][1], acc[t][u], 0, 0, 0);
                    acc[t][u] = __builtin_amdgcn_mfma_f32_32x32x16_bf16(af[t][1], wf[u][0], acc[t][u], 0, 0, 0);
                }
        }
    }

    ln_epilogue<DOUT, OUT_SPLIT, NT>(acc, lnp, bias, gam, bet, Yh, Yl, Yf,
                                     row0, NR, wv, l31, hh);
}

// ---------------------------------------------------------------------------
// Layer 4: Z = H @ W4^T + b4   (128 -> 32, fp32). One thread per row.
// ---------------------------------------------------------------------------
__global__ __launch_bounds__(256)
void layer4_k(const float* __restrict__ H, const float* __restrict__ W4,
              const float* __restrict__ b4, float* __restrict__ Z)
{
    __shared__ float Ws[32 * 128];
    __shared__ float bs[32];
    const int tid = threadIdx.x;
    for (int idx = tid; idx < 4096; idx += 256) Ws[idx] = W4[idx];
    if (tid < 32) bs[tid] = b4[tid];
    __syncthreads();

    long r = (long)blockIdx.x * 256 + tid;
    float acc[32];
#pragma unroll
    for (int c = 0; c < 32; ++c) acc[c] = 0.f;
    for (int k = 0; k < 128; k += 4) {
        float4 x = *(const float4*)(H + r * 128 + k);
#pragma unroll
        for (int c = 0; c < 32; ++c) {
            acc[c] = fmaf(x.x, Ws[c * 128 + k + 0], acc[c]);
            acc[c] = fmaf(x.y, Ws[c * 128 + k + 1], acc[c]);
            acc[c] = fmaf(x.z, Ws[c * 128 + k + 2], acc[c]);
            acc[c] = fmaf(x.w, Ws[c * 128 + k + 3], acc[c]);
        }
    }
#pragma unroll
    for (int c = 0; c < 32; ++c) Z[r * 32 + c] = acc[c] + bs[c];
}

// ---------------------------------------------------------------------------
// Prototypes: one block per class, no atomics.
// ---------------------------------------------------------------------------
__global__ __launch_bounds__(256)
void proto_k(const float* __restrict__ Zs, const int* __restrict__ lab,
             float* __restrict__ P)
{
    const int c = blockIdx.x;
    const int tid = threadIdx.x, lane = tid & 63, wv = tid >> 6;
    float acc[32];
#pragma unroll
    for (int d = 0; d < 32; ++d) acc[d] = 0.f;
    float cnt = 0.f;
    for (int i = tid; i < 32768; i += 256) {
        if (lab[i] == c) {
            cnt += 1.f;
#pragma unroll
            for (int d = 0; d < 32; ++d) acc[d] += Zs[(long)i * 32 + d];
        }
    }
    __shared__ float wsum[4][32];
    __shared__ float wcnt[4];
#pragma unroll
    for (int d = 0; d < 32; ++d) {
        float v = acc[d];
        for (int off = 32; off > 0; off >>= 1) v += __shfl_xor(v, off, 64);
        if (lane == 0) wsum[wv][d] = v;
    }
    {
        float v = cnt;
        for (int off = 32; off > 0; off >>= 1) v += __shfl_xor(v, off, 64);
        if (lane == 0) wcnt[wv] = v;
    }
    __syncthreads();
    if (tid < 32) {
        float s  = wsum[0][tid] + wsum[1][tid] + wsum[2][tid] + wsum[3][tid];
        float cn = wcnt[0] + wcnt[1] + wcnt[2] + wcnt[3];
        P[c * 32 + tid] = s / fmaxf(cn, 1.f);
    }
}

// ---------------------------------------------------------------------------
// -cdist: one thread per query row, protos in LDS.
// ---------------------------------------------------------------------------
__global__ __launch_bounds__(256)
void dist_k(const float* __restrict__ Zq, const float* __restrict__ P,
            float* __restrict__ O)
{
    __shared__ float ps[64 * 32];
    __shared__ float pn[64];
    const int tid = threadIdx.x;
    for (int idx = tid; idx < 2048; idx += 256) ps[idx] = P[idx];
    __syncthreads();
    if (tid < 64) {
        float s = 0.f;
        for (int d = 0; d < 32; ++d) { float v = ps[tid * 32 + d]; s += v * v; }
        pn[tid] = s;
    }
    __syncthreads();

    long q = (long)blockIdx.x * 256 + tid;
    float zr[32];
#pragma unroll
    for (int d = 0; d < 32; d += 4) {
        float4 v = *(const float4*)(Zq + q * 32 + d);
        zr[d] = v.x; zr[d + 1] = v.y; zr[d + 2] = v.z; zr[d + 3] = v.w;
    }
    float zz = 0.f;
#pragma unroll
    for (int d = 0; d < 32; ++d) zz += zr[d] * zr[d];
    for (int p = 0; p < 64; ++p) {
        float dot = 0.f;
#pragma unroll
        for (int d = 0; d < 32; ++d) dot = fmaf(zr[d], ps[p * 32 + d], dot);
        float sq = zz + pn[p] - 2.f * dot;
        O[q * 64 + p] = -sqrtf(fmaxf(sq, 0.f));
    }
}

// ---------------------------------------------------------------------------
// Host side — single pass over all 98304 rows (fits 768 MiB workspace).
// ---------------------------------------------------------------------------
extern "C" void kernel_launch(void* const* d_in, const int* in_sizes, int n_in,
                              void* d_out, int out_size, void* d_ws, size_t ws_size,
                              hipStream_t stream)
{
    const float* supp = (const float*)d_in[0];   // [32768,768]
    const int*   lab  = (const int*)  d_in[1];   // [32768]
    const float* qry  = (const float*)d_in[2];   // [65536,768]
    const float* W1 = (const float*)d_in[3];  const float* b1 = (const float*)d_in[4];
    const float* g1 = (const float*)d_in[5];  const float* be1= (const float*)d_in[6];
    const float* W2 = (const float*)d_in[7];  const float* b2 = (const float*)d_in[8];
    const float* g2 = (const float*)d_in[9];  const float* be2= (const float*)d_in[10];
    const float* W3 = (const float*)d_in[11]; const float* b3 = (const float*)d_in[12];
    const float* g3 = (const float*)d_in[13]; const float* be3= (const float*)d_in[14];
    const float* W4 = (const float*)d_in[15]; const float* b4 = (const float*)d_in[16];
    float* out = (float*)d_out;                  // [65536,64]

    const long NTOT = 98304, NS = 32768, NQ = 65536;
    const int  NR = (int)NTOT;

    char* wsp = (char*)d_ws;
    size_t off = 0;
    auto take = [&](size_t bytes) {
        char* p = wsp + off;
        off += (bytes + 255) & ~(size_t)255;
        return (void*)p;
    };

    float* zAll  = (float*)take((size_t)NTOT * 32 * 4);
    float* proto = (float*)take(2048 * 4);
    u16* W1h = (u16*)take((size_t)512 * 768 * 2);
    u16* W1l = (u16*)take((size_t)512 * 768 * 2);
    u16* W2h = (u16*)take((size_t)512 * 512 * 2);
    u16* W2l = (u16*)take((size_t)512 * 512 * 2);
    u16* W3h = (u16*)take((size_t)128 * 512 * 2);
    u16* W3l = (u16*)take((size_t)128 * 512 * 2);
    u16* h1h = (u16*)take((size_t)NTOT * 512 * 2);
    u16* h1l = (u16*)take((size_t)NTOT * 512 * 2);
    u16* h2h = (u16*)take((size_t)NTOT * 512 * 2);
    u16* h2l = (u16*)take((size_t)NTOT * 512 * 2);
    float* h3 = (float*)take((size_t)NTOT * 128 * 4);
    // total ~468 MB <= 768 MiB ws

    // split+swizzle weights (tiny)
    swizzle_split<<<dim3(32, 4), dim3(256), 0, stream>>>(W1, W1h, W1l, 512, 768);
    swizzle_split<<<dim3(32, 4), dim3(256), 0, stream>>>(W2, W2h, W2l, 512, 512);
    swizzle_split<<<dim3(8, 4),  dim3(256), 0, stream>>>(W3, W3h, W3l, 128, 512);

    // layer 1: fused fp32->split staging; two dispatches (support, query)
    mfma_layer1<512><<<dim3(NS / 64), dim3(256), 0, stream>>>(
        supp, W1h, W1l, b1, g1, be1, h1h, h1l, 768, NR, 0);
    mfma_layer1<512><<<dim3(NQ / 64), dim3(256), 0, stream>>>(
        qry, W1h, W1l, b1, g1, be1, h1h, h1l, 768, NR, NS);

    mfma_layer<512, true><<<dim3(NTOT / 64), dim3(256), 0, stream>>>(
        h1h, h1l, W2h, W2l, b2, g2, be2, h2h, h2l, nullptr, 512, NR);
    mfma_layer<128, false><<<dim3(NTOT / 64), dim3(256), 0, stream>>>(
        h2h, h2l, W3h, W3l, b3, g3, be3, nullptr, nullptr, h3, 512, NR);
    layer4_k<<<dim3(NTOT / 256), dim3(256), 0, stream>>>(h3, W4, b4, zAll);

    proto_k<<<dim3(64),  dim3(256), 0, stream>>>(zAll, lab, proto);
    dist_k<<<dim3(256), dim3(256), 0, stream>>>(zAll + NS * 32, proto, out);
}